// Round 10
// baseline (554.316 us; speedup 1.0000x reference)
//
#include <hip/hip_runtime.h>

#define NROWS    262144   // 16 * 16384
#define DIMS     64
#define KCODES   512
#define MTILE    32       // rows per block
#define RPW      4        // rows per wave (>=5 breaks the <=64-VGPR regime; R4: occ 68->24)
#define CHUNK    256      // epilogue col-half width (col->lane ownership, frozen)
#define NCHUNK   2        // col halves per lane (8 cols/lane total, frozen)
#define D_PER    16       // dims per LDS stage -> 16*512*4 = 32 KB
#define D_CHUNKS 4        // 64 / 16
#define STG4     (D_PER * KCODES / 4)   // float4s per stage = 2048
#define NTHREADS 512

typedef int v8i __attribute__((ext_vector_type(8)));

// DPP lane-xor exchanges (VALU, not DS). quad_perm{1,0,3,2}=0xB1 is exactly
// lane^1; quad_perm{2,3,0,1}=0x4E is exactly lane^2 — same pairing as
// __shfl_xor, so reduction trees using them are bit-identical.
__device__ __forceinline__ float dpp_xor1(float v) {
    int i = __builtin_amdgcn_update_dpp(0, __float_as_int(v), 0xB1, 0xF, 0xF, true);
    return __int_as_float(i);
}
__device__ __forceinline__ float dpp_xor2(float v) {
    int i = __builtin_amdgcn_update_dpp(0, __float_as_int(v), 0x4E, 0xF, 0xF, true);
    return __int_as_float(i);
}

// ---------------------------------------------------------------------------
// prep: embedT[k][d] = embed[d][k]; enorm[k] = sum_d embed[d][k]^2 (numpy
// pairwise-8 order); zero the likelihood accumulator.
// ---------------------------------------------------------------------------
__global__ void prep_kernel(const float* __restrict__ embed,
                            float* __restrict__ embedT,
                            float* __restrict__ enorm,
                            float* __restrict__ lik) {
    int k = blockIdx.x;
    int d = threadIdx.x;
    float v = embed[d * KCODES + k];
    embedT[k * DIMS + d] = v;
    float sq = __fmul_rn(v, v);
    int j = d & 7;
    float r = __shfl(sq, j, 64);
#pragma unroll
    for (int i = 1; i < 8; ++i)
        r = __fadd_rn(r, __shfl(sq, j + 8 * i, 64));
    float t;
    t = __shfl_xor(r, 1, 64); r = __fadd_rn(r, t);
    t = __shfl_xor(r, 2, 64); r = __fadd_rn(r, t);
    t = __shfl_xor(r, 4, 64); r = __fadd_rn(r, t);
    if (d == 0) { enorm[k] = r; lik[k] = 0.0f; }
}

// ---------------------------------------------------------------------------
// main: fused GEMM + softmax + argmax + hard-gather + likelihood partials.
// grid <<<8192, 512>>>. Block: 32 rows x 512 cols; thread owns 4 rows x 8
// cols (acc[2][4][4]); wave = 4 full rows.
//
// ROUND-10 (pipeline round; numerics identical to R9):
// (a) all 8 x s_load_dwordx8 issued at stage top (imm offsets r*256 + ph*32),
//     waited only AFTER the staging barrier -> SMEM latency hides under
//     staging. (R9 waited immediately per phase: 8 serial exposures/block.)
// (b) T14 async-stage split for e: stage dc+1 prefetched into 16 VGPRs
//     during stage dc; ds_write after next barrier1. Barriers are raw
//     s_barrier with an lgkmcnt(0)-only drain before barrier2 (ds_writes
//     visible) — vmcnt is NEVER drained in the loop, so the e-prefetch
//     stays in flight across barriers (__syncthreads would kill it with
//     its vmcnt(0) drain — the m99/m131 structural stall). Previous-stage
//     ds_reads are complete at barrier1 (data already consumed by fma).
// VGPR: 36 + 16 prefetch = ~52..64 (must stay <=64 for the 8-wave regime).
// ---------------------------------------------------------------------------
__launch_bounds__(NTHREADS)
__global__ void main_kernel(const float* __restrict__ x,
                            const float* __restrict__ embed,
                            const float* __restrict__ sigma,
                            const float* __restrict__ embedT,
                            const float* __restrict__ enorm,
                            float* __restrict__ lik,
                            float* __restrict__ out) {
    __shared__ float e_lds[D_PER * KCODES];   // 32 KB

    const int tid = threadIdx.x;
    const int cg  = tid & 63;        // col group (4 cols per half)
    const int rg  = tid >> 6;        // row group (4 rows), == wave id
    const int rowbase = blockIdx.x * MTILE + rg * RPW;

    const float sigma_v = sigma[0];

    float acc[NCHUNK][RPW][4];
#pragma unroll
    for (int c = 0; c < NCHUNK; ++c)
#pragma unroll
        for (int r = 0; r < RPW; ++r)
#pragma unroll
            for (int q = 0; q < 4; ++q) acc[c][r][q] = 0.0f;

    const float4* __restrict__ eg4 = reinterpret_cast<const float4*>(embed);
    float4* e_lds4 = reinterpret_cast<float4*>(e_lds);

    // wave-uniform x base (SGPR): all lanes of this wave share these 4 rows
    const int rg_s = __builtin_amdgcn_readfirstlane(rg);
    const float* xwave = x + (size_t)(blockIdx.x * MTILE + rg_s * RPW) * DIMS;

    // prologue: prefetch stage 0 of e into registers (fire & forget)
    float4 pf0 = eg4[tid];
    float4 pf1 = eg4[tid + NTHREADS];
    float4 pf2 = eg4[tid + 2 * NTHREADS];
    float4 pf3 = eg4[tid + 3 * NTHREADS];

    for (int dc = 0; dc < D_CHUNKS; ++dc) {
        // ---- x rows for this stage, both phases: issue now, wait later.
        // row r at imm r*256 B; phase 1 at +32 B. Completion covered by the
        // lgkm drain at barrier2 + tie-asm below.
        const float* px = xwave + dc * D_PER;
        v8i xs0, xs1, xs2, xs3, ys0, ys1, ys2, ys3;
        asm volatile("s_load_dwordx8 %0, %8, 0\n\t"
                     "s_load_dwordx8 %1, %8, 256\n\t"
                     "s_load_dwordx8 %2, %8, 512\n\t"
                     "s_load_dwordx8 %3, %8, 768\n\t"
                     "s_load_dwordx8 %4, %8, 32\n\t"
                     "s_load_dwordx8 %5, %8, 288\n\t"
                     "s_load_dwordx8 %6, %8, 544\n\t"
                     "s_load_dwordx8 %7, %8, 800"
                     : "=&s"(xs0), "=&s"(xs1), "=&s"(xs2), "=&s"(xs3),
                       "=&s"(ys0), "=&s"(ys1), "=&s"(ys2), "=&s"(ys3)
                     : "s"(px));

        // barrier1: every wave has finished CONSUMING the previous stage's
        // LDS reads (compiler waits data into VGPRs before the fma that uses
        // them) -> plain barrier, no drains; e-prefetch stays in flight.
        __builtin_amdgcn_s_barrier();

        // commit the prefetched stage to LDS (compiler inserts the vmcnt
        // wait for pf* right here, after a full stage of flight time)
        e_lds4[tid]                = pf0;
        e_lds4[tid + NTHREADS]     = pf1;
        e_lds4[tid + 2 * NTHREADS] = pf2;
        e_lds4[tid + 3 * NTHREADS] = pf3;

        // fire prefetch of the NEXT stage (rides across the barrier below)
        if (dc + 1 < D_CHUNKS) {
            const float4* nx = eg4 + (size_t)(dc + 1) * STG4;
            pf0 = nx[tid];
            pf1 = nx[tid + NTHREADS];
            pf2 = nx[tid + 2 * NTHREADS];
            pf3 = nx[tid + 3 * NTHREADS];
        }

        // barrier2: ds_writes must be visible -> drain LGKM ONLY (x s_loads
        // also complete here, for free); vmcnt (e-prefetch) stays in flight.
        asm volatile("s_waitcnt lgkmcnt(0)" ::: "memory");
        __builtin_amdgcn_s_barrier();

        // tie x SGPRs to a post-barrier wait so no consumer hoists above it
        asm volatile("s_waitcnt lgkmcnt(0)"
                     : "+s"(xs0), "+s"(xs1), "+s"(xs2), "+s"(xs3),
                       "+s"(ys0), "+s"(ys1), "+s"(ys2), "+s"(ys3));

        const float4* e4 = reinterpret_cast<const float4*>(e_lds);

#define PHASE(XA, XB, XC, XD, PH)                                             \
        _Pragma("unroll")                                                     \
        for (int d2l = 0; d2l < 4; ++d2l) {                                   \
            const int d2 = (PH) * 4 + d2l;                                    \
            float4 e0a = e4[(2 * d2 + 0) * 128 +  0 + cg];                    \
            float4 e1a = e4[(2 * d2 + 1) * 128 +  0 + cg];                    \
            float4 e0b = e4[(2 * d2 + 0) * 128 + 64 + cg];                    \
            float4 e1b = e4[(2 * d2 + 1) * 128 + 64 + cg];                    \
            ROW_FMA(0, XA) ROW_FMA(1, XB) ROW_FMA(2, XC) ROW_FMA(3, XD)       \
        }
#define ROW_FMA(r, xs)                                                        \
            {                                                                 \
                float xlo = __int_as_float(xs[2 * d2l]);                      \
                float xhi = __int_as_float(xs[2 * d2l + 1]);                  \
                acc[0][r][0] = fmaf(xlo, e0a.x, acc[0][r][0]);                \
                acc[0][r][1] = fmaf(xlo, e0a.y, acc[0][r][1]);                \
                acc[0][r][2] = fmaf(xlo, e0a.z, acc[0][r][2]);                \
                acc[0][r][3] = fmaf(xlo, e0a.w, acc[0][r][3]);                \
                acc[0][r][0] = fmaf(xhi, e1a.x, acc[0][r][0]);                \
                acc[0][r][1] = fmaf(xhi, e1a.y, acc[0][r][1]);                \
                acc[0][r][2] = fmaf(xhi, e1a.z, acc[0][r][2]);                \
                acc[0][r][3] = fmaf(xhi, e1a.w, acc[0][r][3]);                \
                acc[1][r][0] = fmaf(xlo, e0b.x, acc[1][r][0]);                \
                acc[1][r][1] = fmaf(xlo, e0b.y, acc[1][r][1]);                \
                acc[1][r][2] = fmaf(xlo, e0b.z, acc[1][r][2]);                \
                acc[1][r][3] = fmaf(xlo, e0b.w, acc[1][r][3]);                \
                acc[1][r][0] = fmaf(xhi, e1b.x, acc[1][r][0]);                \
                acc[1][r][1] = fmaf(xhi, e1b.y, acc[1][r][1]);                \
                acc[1][r][2] = fmaf(xhi, e1b.z, acc[1][r][2]);                \
                acc[1][r][3] = fmaf(xhi, e1b.w, acc[1][r][3]);                \
            }
        PHASE(xs0, xs1, xs2, xs3, 0)
        PHASE(ys0, ys1, ys2, ys3, 1)
#undef ROW_FMA
#undef PHASE
    }

    // ---- xnorm for the wave's 4 rows, numpy pairwise-8 order ----
    const int r_l = (cg >> 3) & 3;
    const int j_l = cg & 7;
    float xr;
    {
        const float* xp = x + (size_t)(rowbase + r_l) * DIMS + j_l;
        float v0 = xp[0];
        float s = __fmul_rn(v0, v0);
#pragma unroll
        for (int i = 1; i < 8; ++i) {
            float v = xp[8 * i];
            s = __fadd_rn(s, __fmul_rn(v, v));
        }
        xr = s;
    }
    {
        float t;
        t = dpp_xor1(xr);          xr = __fadd_rn(xr, t);
        t = dpp_xor2(xr);          xr = __fadd_rn(xr, t);
        t = __shfl_xor(xr, 4, 64); xr = __fadd_rn(xr, t);
    }

    float en[NCHUNK][4];
#pragma unroll
    for (int c = 0; c < NCHUNK; ++c)
#pragma unroll
        for (int q = 0; q < 4; ++q)
            en[c][q] = enorm[c * CHUNK + cg * 4 + q];

    float likpart[NCHUNK][4];
#pragma unroll
    for (int c = 0; c < NCHUNK; ++c)
#pragma unroll
        for (int q = 0; q < 4; ++q) likpart[c][q] = 0.0f;

#pragma unroll
    for (int r = 0; r < RPW; ++r) {
        float xn = __shfl(xr, r * 8, 64);
        float m = -INFINITY;
#pragma unroll
        for (int c = 0; c < NCHUNK; ++c)
#pragma unroll
            for (int q = 0; q < 4; ++q) {
                float dot  = acc[c][r][q];
                float td   = __fsub_rn(xn, __fmul_rn(2.0f, dot));
                float dist = __fadd_rn(td, en[c][q]);
                float zz   = __fmul_rn(-sigma_v, dist);
                acc[c][r][q] = zz;
                m = fmaxf(m, zz);
            }
        m = fmaxf(m, dpp_xor1(m));
        m = fmaxf(m, dpp_xor2(m));
        m = fmaxf(m, __shfl_xor(m,  4, 64));
        m = fmaxf(m, __shfl_xor(m,  8, 64));
        m = fmaxf(m, __shfl_xor(m, 16, 64));
        m = fmaxf(m, __shfl_xor(m, 32, 64));

        float s = 0.0f;
        int lcol = 1024;
#pragma unroll
        for (int c = 0; c < NCHUNK; ++c)
#pragma unroll
            for (int q = 0; q < 4; ++q) {
                float ee = expf(__fsub_rn(acc[c][r][q], m));
                acc[c][r][q] = ee;
                s += ee;
                int col = c * CHUNK + cg * 4 + q;
                lcol = (ee == 1.0f) ? min(lcol, col) : lcol;
            }
        unsigned long long b0 = __ballot(lcol < CHUNK);
        unsigned long long ba = __ballot(lcol < 1024);
        int srcl = (int)(b0 ? __ffsll(b0) : __ffsll(ba)) - 1;
        int bc = __shfl(lcol, srcl, 64);

        s = __fadd_rn(s, dpp_xor1(s));
        s = __fadd_rn(s, dpp_xor2(s));
        s = __fadd_rn(s, __shfl_xor(s,  4, 64));
        s = __fadd_rn(s, __shfl_xor(s,  8, 64));
        s = __fadd_rn(s, __shfl_xor(s, 16, 64));
        s = __fadd_rn(s, __shfl_xor(s, 32, 64));

        float invS = 1.0f / s;
#pragma unroll
        for (int c = 0; c < NCHUNK; ++c)
#pragma unroll
            for (int q = 0; q < 4; ++q)
                likpart[c][q] = fmaf(acc[c][r][q], invS, likpart[c][q]);

        int row = rowbase + r;
        __builtin_nontemporal_store(embedT[bc * DIMS + cg],
                                    &out[(size_t)row * DIMS + cg]);
    }

    // ---- block-level likelihood reduction (reuse e_lds) ----
    float* red = e_lds;
    __syncthreads();
    red[tid] = 0.0f;
    __syncthreads();
#pragma unroll
    for (int c = 0; c < NCHUNK; ++c)
#pragma unroll
        for (int q = 0; q < 4; ++q)
            atomicAdd(&red[c * CHUNK + cg * 4 + q], likpart[c][q]);
    __syncthreads();
    atomicAdd(&lik[tid], red[tid]);
}

// ---------------------------------------------------------------------------
// finish: likelihoods = lik_sum / N; quant_loss = 0.25 * mean(p*(log p - log(l+eps)))
// ---------------------------------------------------------------------------
__global__ void finish_kernel(const float* __restrict__ lik,
                              float* __restrict__ out) {
    int tid = threadIdx.x;   // 512 threads
    float l = lik[tid] / 262144.0f;     // exact: divide by 2^18
    out[16777217 + tid] = l;
    const float p = 1.0f / 512.0f;
    float term = __fmul_rn(p, __fsub_rn(logf(p), logf(l + 1e-10f)));
#pragma unroll
    for (int mask = 1; mask < 64; mask <<= 1)
        term += __shfl_xor(term, mask, 64);
    __shared__ float ws[8];
    if ((tid & 63) == 0) ws[tid >> 6] = term;
    __syncthreads();
    if (tid == 0) {
        float ssum = 0.0f;
        for (int i = 0; i < 8; ++i) ssum += ws[i];
        out[16777216] = 0.25f * (ssum / 512.0f);
    }
}

extern "C" void kernel_launch(void* const* d_in, const int* in_sizes, int n_in,
                              void* d_out, int out_size, void* d_ws, size_t ws_size,
                              hipStream_t stream) {
    const float* x     = (const float*)d_in[0];
    const float* embed = (const float*)d_in[1];
    const float* sigma = (const float*)d_in[2];
    float* out = (float*)d_out;
    float* ws  = (float*)d_ws;

    float* embedT = ws;             // 512*64 = 32768 floats
    float* enorm  = ws + 32768;     // 512 floats
    float* lik    = ws + 33280;     // 512 floats

    prep_kernel<<<KCODES, DIMS, 0, stream>>>(embed, embedT, enorm, lik);
    main_kernel<<<NROWS / MTILE, NTHREADS, 0, stream>>>(x, embed, sigma,
                                                        embedT, enorm, lik, out);
    finish_kernel<<<1, NTHREADS, 0, stream>>>(lik, out);
}

// Round 11
// 548.047 us; speedup vs baseline: 1.0114x; 1.0114x over previous
//
#include <hip/hip_runtime.h>

#define NROWS    262144   // 16 * 16384
#define DIMS     64
#define KCODES   512
#define MTILE    32       // rows per block
#define RPW      4        // rows per wave (>=5 breaks the <=64-VGPR regime; R4: occ 68->24)
#define CHUNK    256      // epilogue col-half width (col->lane ownership, frozen)
#define NCHUNK   2        // col halves per lane (8 cols/lane total, frozen)
#define D_PER    16       // dims per stage
#define D_CHUNKS 4        // 64 / 16
#define NTHREADS 512

typedef int v8i __attribute__((ext_vector_type(8)));

// DPP lane-xor exchanges (VALU, not DS). quad_perm{1,0,3,2}=0xB1 is exactly
// lane^1; quad_perm{2,3,0,1}=0x4E is exactly lane^2 — same pairing as
// __shfl_xor, so reduction trees using them are bit-identical.
__device__ __forceinline__ float dpp_xor1(float v) {
    int i = __builtin_amdgcn_update_dpp(0, __float_as_int(v), 0xB1, 0xF, 0xF, true);
    return __int_as_float(i);
}
__device__ __forceinline__ float dpp_xor2(float v) {
    int i = __builtin_amdgcn_update_dpp(0, __float_as_int(v), 0x4E, 0xF, 0xF, true);
    return __int_as_float(i);
}

// ---------------------------------------------------------------------------
// prep: embedT[k][d] = embed[d][k]; enorm[k] = sum_d embed[d][k]^2 (numpy
// pairwise-8 order); zero the likelihood accumulator.
// ---------------------------------------------------------------------------
__global__ void prep_kernel(const float* __restrict__ embed,
                            float* __restrict__ embedT,
                            float* __restrict__ enorm,
                            float* __restrict__ lik) {
    int k = blockIdx.x;
    int d = threadIdx.x;
    float v = embed[d * KCODES + k];
    embedT[k * DIMS + d] = v;
    float sq = __fmul_rn(v, v);
    int j = d & 7;
    float r = __shfl(sq, j, 64);
#pragma unroll
    for (int i = 1; i < 8; ++i)
        r = __fadd_rn(r, __shfl(sq, j + 8 * i, 64));
    float t;
    t = __shfl_xor(r, 1, 64); r = __fadd_rn(r, t);
    t = __shfl_xor(r, 2, 64); r = __fadd_rn(r, t);
    t = __shfl_xor(r, 4, 64); r = __fadd_rn(r, t);
    if (d == 0) { enorm[k] = r; lik[k] = 0.0f; }
}

// ---------------------------------------------------------------------------
// main: fused GEMM + softmax + argmax + hard-gather + likelihood partials.
// grid <<<8192, 512>>>. Block: 32 rows x 512 cols; thread owns 4 rows x 8
// cols (acc[2][4][4]); wave = 4 full rows. R9 structure (best: 473us).
//
// ROUND-11: e-reads split across the DS and VMEM pipes. R9 counters: VALU
// busy ~236us, GEMM ds_read ~164us on the per-CU DS unit, VMEM idle during
// GEMM (x is on the scalar pipe since R9). Change: stage only cols 0-255 in
// LDS (16KB/stage, staging cost halves); read cols 256-511 directly from
// global — e is 128KB, L2/L3-resident, and the lane pattern is a perfectly
// coalesced 1KB wave-load. DS GEMM traffic halves (~82us); the global half
// rides the idle L1/TA pipe. Identical float values, identical fma chains
// and reduction trees -> bit-exact. Everything else byte-for-byte R9.
// Lessons kept: RPW=4 / VGPR<=64 (R4); no full unroll (R5); no async-LDS
// staging (R6); no raw-barrier pipelining (R10); x via s_load_dwordx8 with
// in-asm lgkmcnt wait (R9).
// ---------------------------------------------------------------------------
__launch_bounds__(NTHREADS)
__global__ void main_kernel(const float* __restrict__ x,
                            const float* __restrict__ embed,
                            const float* __restrict__ sigma,
                            const float* __restrict__ embedT,
                            const float* __restrict__ enorm,
                            float* __restrict__ lik,
                            float* __restrict__ out) {
    __shared__ float e_lds[D_PER * CHUNK];   // 16 KB (cols 0-255 only)

    const int tid = threadIdx.x;
    const int cg  = tid & 63;        // col group (4 cols per half)
    const int rg  = tid >> 6;        // row group (4 rows), == wave id
    const int rowbase = blockIdx.x * MTILE + rg * RPW;

    const float sigma_v = sigma[0];

    float acc[NCHUNK][RPW][4];
#pragma unroll
    for (int c = 0; c < NCHUNK; ++c)
#pragma unroll
        for (int r = 0; r < RPW; ++r)
#pragma unroll
            for (int q = 0; q < 4; ++q) acc[c][r][q] = 0.0f;

    const float4* __restrict__ eg4 = reinterpret_cast<const float4*>(embed);
    float4* e_lds4 = reinterpret_cast<float4*>(e_lds);

    // wave-uniform x base (SGPR): all lanes of this wave share these 4 rows
    const int rg_s = __builtin_amdgcn_readfirstlane(rg);
    const float* xwave = x + (size_t)(blockIdx.x * MTILE + rg_s * RPW) * DIMS;

    for (int dc = 0; dc < D_CHUNKS; ++dc) {
        __syncthreads();   // protect previous stage's readers
        // stage e[dc*16 .. dc*16+15][cols 0..255]: 1024 float4s, 2 per thread
#pragma unroll
        for (int i = 0; i < 2; ++i) {
            int f4 = tid + i * NTHREADS;          // 0..1023
            int d  = f4 >> 6;                     // dim within stage
            int c4 = f4 & 63;                     // float4-col within half 0
            e_lds4[d * 64 + c4] = eg4[(size_t)(dc * D_PER + d) * 128 + c4];
        }
        __syncthreads();

        const float4* e4 = reinterpret_cast<const float4*>(e_lds);
        const float4* egs = eg4 + (size_t)dc * D_PER * 128;   // stage base

#pragma unroll
        for (int ph = 0; ph < 2; ++ph) {
            // 4 rows x 8 dims (32 B/row) into SGPRs; wait folded into the
            // asm so every consumer data-depends on completed loads.
            const float* p0 = xwave + 0 * DIMS + dc * D_PER + ph * 8;
            const float* p1 = xwave + 1 * DIMS + dc * D_PER + ph * 8;
            const float* p2 = xwave + 2 * DIMS + dc * D_PER + ph * 8;
            const float* p3 = xwave + 3 * DIMS + dc * D_PER + ph * 8;
            v8i xs0, xs1, xs2, xs3;
            asm volatile("s_load_dwordx8 %0, %4, 0\n\t"
                         "s_load_dwordx8 %1, %5, 0\n\t"
                         "s_load_dwordx8 %2, %6, 0\n\t"
                         "s_load_dwordx8 %3, %7, 0\n\t"
                         "s_waitcnt lgkmcnt(0)"
                         : "=&s"(xs0), "=&s"(xs1), "=&s"(xs2), "=&s"(xs3)
                         : "s"(p0), "s"(p1), "s"(p2), "s"(p3));

#pragma unroll
            for (int d2l = 0; d2l < 4; ++d2l) {   // dim pairs within phase
                const int d2 = ph * 4 + d2l;
                // half 0 from LDS (16-bit imm offsets, stage = 16KB)
                float4 e0a = e4[(2 * d2 + 0) * 64 + cg];        // dim lo, h0
                float4 e1a = e4[(2 * d2 + 1) * 64 + cg];        // dim hi, h0
                // half 1 direct from global (L1/L2-resident, coalesced 1KB)
                float4 e0b = egs[(2 * d2 + 0) * 128 + 64 + cg]; // dim lo, h1
                float4 e1b = egs[(2 * d2 + 1) * 128 + 64 + cg]; // dim hi, h1

#define ROW_FMA(r, xs)                                                        \
                {                                                             \
                    float xlo = __int_as_float(xs[2 * d2l]);                  \
                    float xhi = __int_as_float(xs[2 * d2l + 1]);              \
                    acc[0][r][0] = fmaf(xlo, e0a.x, acc[0][r][0]);            \
                    acc[0][r][1] = fmaf(xlo, e0a.y, acc[0][r][1]);            \
                    acc[0][r][2] = fmaf(xlo, e0a.z, acc[0][r][2]);            \
                    acc[0][r][3] = fmaf(xlo, e0a.w, acc[0][r][3]);            \
                    acc[0][r][0] = fmaf(xhi, e1a.x, acc[0][r][0]);            \
                    acc[0][r][1] = fmaf(xhi, e1a.y, acc[0][r][1]);            \
                    acc[0][r][2] = fmaf(xhi, e1a.z, acc[0][r][2]);            \
                    acc[0][r][3] = fmaf(xhi, e1a.w, acc[0][r][3]);            \
                    acc[1][r][0] = fmaf(xlo, e0b.x, acc[1][r][0]);            \
                    acc[1][r][1] = fmaf(xlo, e0b.y, acc[1][r][1]);            \
                    acc[1][r][2] = fmaf(xlo, e0b.z, acc[1][r][2]);            \
                    acc[1][r][3] = fmaf(xlo, e0b.w, acc[1][r][3]);            \
                    acc[1][r][0] = fmaf(xhi, e1b.x, acc[1][r][0]);            \
                    acc[1][r][1] = fmaf(xhi, e1b.y, acc[1][r][1]);            \
                    acc[1][r][2] = fmaf(xhi, e1b.z, acc[1][r][2]);            \
                    acc[1][r][3] = fmaf(xhi, e1b.w, acc[1][r][3]);            \
                }
                ROW_FMA(0, xs0)
                ROW_FMA(1, xs1)
                ROW_FMA(2, xs2)
                ROW_FMA(3, xs3)
#undef ROW_FMA
            }
        }
    }

    // ---- xnorm for the wave's 4 rows, numpy pairwise-8 order ----
    const int r_l = (cg >> 3) & 3;
    const int j_l = cg & 7;
    float xr;
    {
        const float* xp = x + (size_t)(rowbase + r_l) * DIMS + j_l;
        float v0 = xp[0];
        float s = __fmul_rn(v0, v0);
#pragma unroll
        for (int i = 1; i < 8; ++i) {
            float v = xp[8 * i];
            s = __fadd_rn(s, __fmul_rn(v, v));
        }
        xr = s;
    }
    {
        float t;
        t = dpp_xor1(xr);          xr = __fadd_rn(xr, t);
        t = dpp_xor2(xr);          xr = __fadd_rn(xr, t);
        t = __shfl_xor(xr, 4, 64); xr = __fadd_rn(xr, t);
    }

    float en[NCHUNK][4];
#pragma unroll
    for (int c = 0; c < NCHUNK; ++c)
#pragma unroll
        for (int q = 0; q < 4; ++q)
            en[c][q] = enorm[c * CHUNK + cg * 4 + q];

    float likpart[NCHUNK][4];
#pragma unroll
    for (int c = 0; c < NCHUNK; ++c)
#pragma unroll
        for (int q = 0; q < 4; ++q) likpart[c][q] = 0.0f;

#pragma unroll
    for (int r = 0; r < RPW; ++r) {
        float xn = __shfl(xr, r * 8, 64);
        float m = -INFINITY;
#pragma unroll
        for (int c = 0; c < NCHUNK; ++c)
#pragma unroll
            for (int q = 0; q < 4; ++q) {
                float dot  = acc[c][r][q];
                float td   = __fsub_rn(xn, __fmul_rn(2.0f, dot));
                float dist = __fadd_rn(td, en[c][q]);
                float zz   = __fmul_rn(-sigma_v, dist);
                acc[c][r][q] = zz;
                m = fmaxf(m, zz);
            }
        m = fmaxf(m, dpp_xor1(m));
        m = fmaxf(m, dpp_xor2(m));
        m = fmaxf(m, __shfl_xor(m,  4, 64));
        m = fmaxf(m, __shfl_xor(m,  8, 64));
        m = fmaxf(m, __shfl_xor(m, 16, 64));
        m = fmaxf(m, __shfl_xor(m, 32, 64));

        float s = 0.0f;
        int lcol = 1024;
#pragma unroll
        for (int c = 0; c < NCHUNK; ++c)
#pragma unroll
            for (int q = 0; q < 4; ++q) {
                float ee = expf(__fsub_rn(acc[c][r][q], m));
                acc[c][r][q] = ee;
                s += ee;
                int col = c * CHUNK + cg * 4 + q;
                lcol = (ee == 1.0f) ? min(lcol, col) : lcol;
            }
        unsigned long long b0 = __ballot(lcol < CHUNK);
        unsigned long long ba = __ballot(lcol < 1024);
        int srcl = (int)(b0 ? __ffsll(b0) : __ffsll(ba)) - 1;
        int bc = __shfl(lcol, srcl, 64);

        s = __fadd_rn(s, dpp_xor1(s));
        s = __fadd_rn(s, dpp_xor2(s));
        s = __fadd_rn(s, __shfl_xor(s,  4, 64));
        s = __fadd_rn(s, __shfl_xor(s,  8, 64));
        s = __fadd_rn(s, __shfl_xor(s, 16, 64));
        s = __fadd_rn(s, __shfl_xor(s, 32, 64));

        float invS = 1.0f / s;
#pragma unroll
        for (int c = 0; c < NCHUNK; ++c)
#pragma unroll
            for (int q = 0; q < 4; ++q)
                likpart[c][q] = fmaf(acc[c][r][q], invS, likpart[c][q]);

        int row = rowbase + r;
        __builtin_nontemporal_store(embedT[bc * DIMS + cg],
                                    &out[(size_t)row * DIMS + cg]);
    }

    // ---- block-level likelihood reduction (reuse e_lds; 2KB needed) ----
    float* red = e_lds;
    __syncthreads();
    red[tid] = 0.0f;
    __syncthreads();
#pragma unroll
    for (int c = 0; c < NCHUNK; ++c)
#pragma unroll
        for (int q = 0; q < 4; ++q)
            atomicAdd(&red[c * CHUNK + cg * 4 + q], likpart[c][q]);
    __syncthreads();
    atomicAdd(&lik[tid], red[tid]);
}

// ---------------------------------------------------------------------------
// finish: likelihoods = lik_sum / N; quant_loss = 0.25 * mean(p*(log p - log(l+eps)))
// ---------------------------------------------------------------------------
__global__ void finish_kernel(const float* __restrict__ lik,
                              float* __restrict__ out) {
    int tid = threadIdx.x;   // 512 threads
    float l = lik[tid] / 262144.0f;     // exact: divide by 2^18
    out[16777217 + tid] = l;
    const float p = 1.0f / 512.0f;
    float term = __fmul_rn(p, __fsub_rn(logf(p), logf(l + 1e-10f)));
#pragma unroll
    for (int mask = 1; mask < 64; mask <<= 1)
        term += __shfl_xor(term, mask, 64);
    __shared__ float ws[8];
    if ((tid & 63) == 0) ws[tid >> 6] = term;
    __syncthreads();
    if (tid == 0) {
        float ssum = 0.0f;
        for (int i = 0; i < 8; ++i) ssum += ws[i];
        out[16777216] = 0.25f * (ssum / 512.0f);
    }
}

extern "C" void kernel_launch(void* const* d_in, const int* in_sizes, int n_in,
                              void* d_out, int out_size, void* d_ws, size_t ws_size,
                              hipStream_t stream) {
    const float* x     = (const float*)d_in[0];
    const float* embed = (const float*)d_in[1];
    const float* sigma = (const float*)d_in[2];
    float* out = (float*)d_out;
    float* ws  = (float*)d_ws;

    float* embedT = ws;             // 512*64 = 32768 floats
    float* enorm  = ws + 32768;     // 512 floats
    float* lik    = ws + 33280;     // 512 floats

    prep_kernel<<<KCODES, DIMS, 0, stream>>>(embed, embedT, enorm, lik);
    main_kernel<<<NROWS / MTILE, NTHREADS, 0, stream>>>(x, embed, sigma,
                                                        embedT, enorm, lik, out);
    finish_kernel<<<1, NTHREADS, 0, stream>>>(lik, out);
}

// Round 12
// 469.696 us; speedup vs baseline: 1.1802x; 1.1668x over previous
//
#include <hip/hip_runtime.h>

#define NROWS    262144   // 16 * 16384
#define DIMS     64
#define KCODES   512
#define MTILE    32       // rows per block
#define RPW      4        // rows per wave (>=5 breaks the <=64-VGPR regime; R4: occ 68->24)
#define CHUNK    256      // epilogue col-half width (col->lane ownership, frozen)
#define NCHUNK   2        // col halves per lane (8 cols/lane total, frozen)
#define D_PER    16       // dims per x-s_load batch
#define D_CHUNKS 4        // 64 / 16
#define NTHREADS 512

typedef int v8i __attribute__((ext_vector_type(8)));

// DPP lane-xor exchanges (VALU, not DS). quad_perm{1,0,3,2}=0xB1 is exactly
// lane^1; quad_perm{2,3,0,1}=0x4E is exactly lane^2 — same pairing as
// __shfl_xor, so reduction trees using them are bit-identical.
__device__ __forceinline__ float dpp_xor1(float v) {
    int i = __builtin_amdgcn_update_dpp(0, __float_as_int(v), 0xB1, 0xF, 0xF, true);
    return __int_as_float(i);
}
__device__ __forceinline__ float dpp_xor2(float v) {
    int i = __builtin_amdgcn_update_dpp(0, __float_as_int(v), 0x4E, 0xF, 0xF, true);
    return __int_as_float(i);
}

// ---------------------------------------------------------------------------
// prep: embedT[k][d] = embed[d][k]; enorm[k] = sum_d embed[d][k]^2 (numpy
// pairwise-8 order); zero the likelihood accumulator.
// ---------------------------------------------------------------------------
__global__ void prep_kernel(const float* __restrict__ embed,
                            float* __restrict__ embedT,
                            float* __restrict__ enorm,
                            float* __restrict__ lik) {
    int k = blockIdx.x;
    int d = threadIdx.x;
    float v = embed[d * KCODES + k];
    embedT[k * DIMS + d] = v;
    float sq = __fmul_rn(v, v);
    int j = d & 7;
    float r = __shfl(sq, j, 64);
#pragma unroll
    for (int i = 1; i < 8; ++i)
        r = __fadd_rn(r, __shfl(sq, j + 8 * i, 64));
    float t;
    t = __shfl_xor(r, 1, 64); r = __fadd_rn(r, t);
    t = __shfl_xor(r, 2, 64); r = __fadd_rn(r, t);
    t = __shfl_xor(r, 4, 64); r = __fadd_rn(r, t);
    if (d == 0) { enorm[k] = r; lik[k] = 0.0f; }
}

// ---------------------------------------------------------------------------
// main: fused GEMM + softmax + argmax + hard-gather + likelihood partials.
// grid <<<8192, 512>>>. Block: 32 rows x 512 cols; thread owns 4 rows x 8
// cols (acc[2][4][4]); wave = 4 full rows.
//
// ROUND-12: NO LDS STAGING AT ALL — e read directly from global every use.
// Rationale (catalog common-mistake #7: "don't LDS-stage data that
// cache-fits"): e is 128 KB, L2/L3-resident for the whole kernel, and
// eg4[d*128 + half*64 + cg] is a perfectly coalesced 1KB wave-load. Staging
// bought e-reuse on the DS pipe but cost: ~164us GEMM ds_read + ~20us
// ds_write on the per-CU shared DS unit, plus 8 barriers/block that convoy
// all 8 waves (every scheduling fix around those barriers failed: R5/R6/
// R10/R11 all lost occupancy 66->46). Dropping staging deletes the barriers
// and the DS GEMM traffic entirely; e-reads ride the TA/L1/L2 path, idle
// since R9 moved x to the scalar pipe. Waves self-schedule; ~5 waves/SIMD
// of TLP hide the L1/L2 latency. Identical float values, identical fma
// chains -> bit-exact. x stays on SGPRs (R9 win: s_load_dwordx8 + in-asm
// lgkmcnt wait). LDS shrinks to a 2KB lik-reduction buffer.
// Fail criterion (pre-committed): dur > 490us or occ < 60% -> L1/L2 can't
// match DS feed rate; revert to R9 and declare the DS<->VALU floor.
// ---------------------------------------------------------------------------
__launch_bounds__(NTHREADS)
__global__ void main_kernel(const float* __restrict__ x,
                            const float* __restrict__ embed,
                            const float* __restrict__ sigma,
                            const float* __restrict__ embedT,
                            const float* __restrict__ enorm,
                            float* __restrict__ lik,
                            float* __restrict__ out) {
    __shared__ float red_lds[NTHREADS];   // 2 KB, lik reduction only

    const int tid = threadIdx.x;
    const int cg  = tid & 63;        // col group (4 cols per half)
    const int rg  = tid >> 6;        // row group (4 rows), == wave id
    const int rowbase = blockIdx.x * MTILE + rg * RPW;

    const float sigma_v = sigma[0];

    float acc[NCHUNK][RPW][4];
#pragma unroll
    for (int c = 0; c < NCHUNK; ++c)
#pragma unroll
        for (int r = 0; r < RPW; ++r)
#pragma unroll
            for (int q = 0; q < 4; ++q) acc[c][r][q] = 0.0f;

    const float4* __restrict__ eg4 = reinterpret_cast<const float4*>(embed);

    // wave-uniform x base (SGPR): all lanes of this wave share these 4 rows
    const int rg_s = __builtin_amdgcn_readfirstlane(rg);
    const float* xwave = x + (size_t)(blockIdx.x * MTILE + rg_s * RPW) * DIMS;

    for (int dc = 0; dc < D_CHUNKS; ++dc) {
#pragma unroll
        for (int ph = 0; ph < 2; ++ph) {
            // 4 rows x 8 dims (32 B/row) into SGPRs; wait folded into the
            // asm so every consumer data-depends on completed loads.
            const float* p0 = xwave + 0 * DIMS + dc * D_PER + ph * 8;
            const float* p1 = xwave + 1 * DIMS + dc * D_PER + ph * 8;
            const float* p2 = xwave + 2 * DIMS + dc * D_PER + ph * 8;
            const float* p3 = xwave + 3 * DIMS + dc * D_PER + ph * 8;
            v8i xs0, xs1, xs2, xs3;
            asm volatile("s_load_dwordx8 %0, %4, 0\n\t"
                         "s_load_dwordx8 %1, %5, 0\n\t"
                         "s_load_dwordx8 %2, %6, 0\n\t"
                         "s_load_dwordx8 %3, %7, 0\n\t"
                         "s_waitcnt lgkmcnt(0)"
                         : "=&s"(xs0), "=&s"(xs1), "=&s"(xs2), "=&s"(xs3)
                         : "s"(p0), "s"(p1), "s"(p2), "s"(p3));

#pragma unroll
            for (int d2l = 0; d2l < 4; ++d2l) {   // dim pairs within phase
                const int d2  = ph * 4 + d2l;
                const int dlo = dc * D_PER + 2 * d2;   // global dim (even)
                // e direct from global: coalesced 1KB wave-loads, L1/L2-hit
                float4 e0a = eg4[(size_t)(dlo + 0) * 128 +  0 + cg];  // lo,h0
                float4 e1a = eg4[(size_t)(dlo + 1) * 128 +  0 + cg];  // hi,h0
                float4 e0b = eg4[(size_t)(dlo + 0) * 128 + 64 + cg];  // lo,h1
                float4 e1b = eg4[(size_t)(dlo + 1) * 128 + 64 + cg];  // hi,h1

#define ROW_FMA(r, xs)                                                        \
                {                                                             \
                    float xlo = __int_as_float(xs[2 * d2l]);                  \
                    float xhi = __int_as_float(xs[2 * d2l + 1]);              \
                    acc[0][r][0] = fmaf(xlo, e0a.x, acc[0][r][0]);            \
                    acc[0][r][1] = fmaf(xlo, e0a.y, acc[0][r][1]);            \
                    acc[0][r][2] = fmaf(xlo, e0a.z, acc[0][r][2]);            \
                    acc[0][r][3] = fmaf(xlo, e0a.w, acc[0][r][3]);            \
                    acc[0][r][0] = fmaf(xhi, e1a.x, acc[0][r][0]);            \
                    acc[0][r][1] = fmaf(xhi, e1a.y, acc[0][r][1]);            \
                    acc[0][r][2] = fmaf(xhi, e1a.z, acc[0][r][2]);            \
                    acc[0][r][3] = fmaf(xhi, e1a.w, acc[0][r][3]);            \
                    acc[1][r][0] = fmaf(xlo, e0b.x, acc[1][r][0]);            \
                    acc[1][r][1] = fmaf(xlo, e0b.y, acc[1][r][1]);            \
                    acc[1][r][2] = fmaf(xlo, e0b.z, acc[1][r][2]);            \
                    acc[1][r][3] = fmaf(xlo, e0b.w, acc[1][r][3]);            \
                    acc[1][r][0] = fmaf(xhi, e1b.x, acc[1][r][0]);            \
                    acc[1][r][1] = fmaf(xhi, e1b.y, acc[1][r][1]);            \
                    acc[1][r][2] = fmaf(xhi, e1b.z, acc[1][r][2]);            \
                    acc[1][r][3] = fmaf(xhi, e1b.w, acc[1][r][3]);            \
                }
                ROW_FMA(0, xs0)
                ROW_FMA(1, xs1)
                ROW_FMA(2, xs2)
                ROW_FMA(3, xs3)
#undef ROW_FMA
            }
        }
    }

    // ---- xnorm for the wave's 4 rows, numpy pairwise-8 order ----
    const int r_l = (cg >> 3) & 3;
    const int j_l = cg & 7;
    float xr;
    {
        const float* xp = x + (size_t)(rowbase + r_l) * DIMS + j_l;
        float v0 = xp[0];
        float s = __fmul_rn(v0, v0);
#pragma unroll
        for (int i = 1; i < 8; ++i) {
            float v = xp[8 * i];
            s = __fadd_rn(s, __fmul_rn(v, v));
        }
        xr = s;
    }
    {
        float t;
        t = dpp_xor1(xr);          xr = __fadd_rn(xr, t);
        t = dpp_xor2(xr);          xr = __fadd_rn(xr, t);
        t = __shfl_xor(xr, 4, 64); xr = __fadd_rn(xr, t);
    }

    float en[NCHUNK][4];
#pragma unroll
    for (int c = 0; c < NCHUNK; ++c)
#pragma unroll
        for (int q = 0; q < 4; ++q)
            en[c][q] = enorm[c * CHUNK + cg * 4 + q];

    float likpart[NCHUNK][4];
#pragma unroll
    for (int c = 0; c < NCHUNK; ++c)
#pragma unroll
        for (int q = 0; q < 4; ++q) likpart[c][q] = 0.0f;

#pragma unroll
    for (int r = 0; r < RPW; ++r) {
        float xn = __shfl(xr, r * 8, 64);
        float m = -INFINITY;
#pragma unroll
        for (int c = 0; c < NCHUNK; ++c)
#pragma unroll
            for (int q = 0; q < 4; ++q) {
                float dot  = acc[c][r][q];
                float td   = __fsub_rn(xn, __fmul_rn(2.0f, dot));
                float dist = __fadd_rn(td, en[c][q]);
                float zz   = __fmul_rn(-sigma_v, dist);
                acc[c][r][q] = zz;
                m = fmaxf(m, zz);
            }
        m = fmaxf(m, dpp_xor1(m));
        m = fmaxf(m, dpp_xor2(m));
        m = fmaxf(m, __shfl_xor(m,  4, 64));
        m = fmaxf(m, __shfl_xor(m,  8, 64));
        m = fmaxf(m, __shfl_xor(m, 16, 64));
        m = fmaxf(m, __shfl_xor(m, 32, 64));

        float s = 0.0f;
        int lcol = 1024;
#pragma unroll
        for (int c = 0; c < NCHUNK; ++c)
#pragma unroll
            for (int q = 0; q < 4; ++q) {
                float ee = expf(__fsub_rn(acc[c][r][q], m));
                acc[c][r][q] = ee;
                s += ee;
                int col = c * CHUNK + cg * 4 + q;
                lcol = (ee == 1.0f) ? min(lcol, col) : lcol;
            }
        unsigned long long b0 = __ballot(lcol < CHUNK);
        unsigned long long ba = __ballot(lcol < 1024);
        int srcl = (int)(b0 ? __ffsll(b0) : __ffsll(ba)) - 1;
        int bc = __shfl(lcol, srcl, 64);

        s = __fadd_rn(s, dpp_xor1(s));
        s = __fadd_rn(s, dpp_xor2(s));
        s = __fadd_rn(s, __shfl_xor(s,  4, 64));
        s = __fadd_rn(s, __shfl_xor(s,  8, 64));
        s = __fadd_rn(s, __shfl_xor(s, 16, 64));
        s = __fadd_rn(s, __shfl_xor(s, 32, 64));

        float invS = 1.0f / s;
#pragma unroll
        for (int c = 0; c < NCHUNK; ++c)
#pragma unroll
            for (int q = 0; q < 4; ++q)
                likpart[c][q] = fmaf(acc[c][r][q], invS, likpart[c][q]);

        int row = rowbase + r;
        __builtin_nontemporal_store(embedT[bc * DIMS + cg],
                                    &out[(size_t)row * DIMS + cg]);
    }

    // ---- block-level likelihood reduction ----
    red_lds[tid] = 0.0f;
    __syncthreads();
#pragma unroll
    for (int c = 0; c < NCHUNK; ++c)
#pragma unroll
        for (int q = 0; q < 4; ++q)
            atomicAdd(&red_lds[c * CHUNK + cg * 4 + q], likpart[c][q]);
    __syncthreads();
    atomicAdd(&lik[tid], red_lds[tid]);
}

// ---------------------------------------------------------------------------
// finish: likelihoods = lik_sum / N; quant_loss = 0.25 * mean(p*(log p - log(l+eps)))
// ---------------------------------------------------------------------------
__global__ void finish_kernel(const float* __restrict__ lik,
                              float* __restrict__ out) {
    int tid = threadIdx.x;   // 512 threads
    float l = lik[tid] / 262144.0f;     // exact: divide by 2^18
    out[16777217 + tid] = l;
    const float p = 1.0f / 512.0f;
    float term = __fmul_rn(p, __fsub_rn(logf(p), logf(l + 1e-10f)));
#pragma unroll
    for (int mask = 1; mask < 64; mask <<= 1)
        term += __shfl_xor(term, mask, 64);
    __shared__ float ws[8];
    if ((tid & 63) == 0) ws[tid >> 6] = term;
    __syncthreads();
    if (tid == 0) {
        float ssum = 0.0f;
        for (int i = 0; i < 8; ++i) ssum += ws[i];
        out[16777216] = 0.25f * (ssum / 512.0f);
    }
}

extern "C" void kernel_launch(void* const* d_in, const int* in_sizes, int n_in,
                              void* d_out, int out_size, void* d_ws, size_t ws_size,
                              hipStream_t stream) {
    const float* x     = (const float*)d_in[0];
    const float* embed = (const float*)d_in[1];
    const float* sigma = (const float*)d_in[2];
    float* out = (float*)d_out;
    float* ws  = (float*)d_ws;

    float* embedT = ws;             // 512*64 = 32768 floats
    float* enorm  = ws + 32768;     // 512 floats
    float* lik    = ws + 33280;     // 512 floats

    prep_kernel<<<KCODES, DIMS, 0, stream>>>(embed, embedT, enorm, lik);
    main_kernel<<<NROWS / MTILE, NTHREADS, 0, stream>>>(x, embed, sigma,
                                                        embedT, enorm, lik, out);
    finish_kernel<<<1, NTHREADS, 0, stream>>>(lik, out);
}